// Round 1
// baseline (24.768 us; speedup 1.0000x reference)
//
#include <hip/hip_runtime.h>
#include <hip/hip_bf16.h>

// Problem constants from setup_inputs(): x:[8,160,160,64] f32, pos:[8,4096,2] f32,
// H=W=1280 (int scalars on device). out:[8,4096,64] f32.
constexpr int B  = 8;
constexpr int Hf = 160;
constexpr int Wf = 160;
constexpr int C  = 64;
constexpr int N  = 4096;

// Bicubic (cubic convolution) weights, A = -0.75, taps at offsets -1,0,1,2.
__device__ __forceinline__ void cubic_weights(float t, float w[4]) {
    const float A = -0.75f;
    // w_in(s) for |s|<=1:  ((A+2)s - (A+3)) s^2 + 1
    // w_out(s) for 1<|s|<2: ((A s - 5A)s + 8A)s - 4A
    float s;
    s = t + 1.0f;                       // tap -1, s in [1,2)
    w[0] = ((A * s - 5.0f * A) * s + 8.0f * A) * s - 4.0f * A;
    s = t;                              // tap 0, s in [0,1)
    w[1] = ((A + 2.0f) * s - (A + 3.0f)) * s * s + 1.0f;
    s = 1.0f - t;                       // tap 1
    w[2] = ((A + 2.0f) * s - (A + 3.0f)) * s * s + 1.0f;
    s = 2.0f - t;                       // tap 2, s in (1,2]
    w[3] = ((A * s - 5.0f * A) * s + 8.0f * A) * s - 4.0f * A;
}

__global__ __launch_bounds__(256)
void interp_sparse_bicubic(const float* __restrict__ x,
                           const float* __restrict__ pos,
                           const int* __restrict__ Hp,
                           const int* __restrict__ Wp,
                           float* __restrict__ out) {
    // 16 lanes per point; each lane owns one float4 channel-quad (C=64 -> 16 quads).
    int t = blockIdx.x * blockDim.x + threadIdx.x;
    int q   = t & 15;        // channel quad index
    int pnt = t >> 4;        // global point index in [0, B*N)
    if (pnt >= B * N) return;

    int b = pnt / N;

    float px = pos[(size_t)pnt * 2 + 0];
    float py = pos[(size_t)pnt * 2 + 1];
    float Wo = (float)Wp[0];
    float Ho = (float)Hp[0];

    // Match reference math exactly (align_corners=False chain).
    float gx = 2.0f * px / (Wo - 1.0f) - 1.0f;
    float gy = 2.0f * py / (Ho - 1.0f) - 1.0f;
    float ix = ((gx + 1.0f) * (float)Wf - 1.0f) * 0.5f;
    float iy = ((gy + 1.0f) * (float)Hf - 1.0f) * 0.5f;

    float fx = floorf(ix), fy = floorf(iy);
    float tx = ix - fx,    ty = iy - fy;
    int x0 = (int)fx, y0 = (int)fy;

    float wx[4], wy[4];
    cubic_weights(tx, wx);
    cubic_weights(ty, wy);

    const float* xb = x + (size_t)b * (Hf * Wf * C) + q * 4;

    float4 acc = make_float4(0.f, 0.f, 0.f, 0.f);

    #pragma unroll
    for (int i = 0; i < 4; ++i) {
        int yi = y0 - 1 + i;
        if (yi < 0 || yi >= Hf) continue;   // zeros padding
        float wyi = wy[i];
        const float* row = xb + (size_t)yi * (Wf * C);
        #pragma unroll
        for (int j = 0; j < 4; ++j) {
            int xj = x0 - 1 + j;
            if (xj < 0 || xj >= Wf) continue;
            float w = wyi * wx[j];
            float4 v = *reinterpret_cast<const float4*>(row + (size_t)xj * C);
            acc.x = fmaf(w, v.x, acc.x);
            acc.y = fmaf(w, v.y, acc.y);
            acc.z = fmaf(w, v.z, acc.z);
            acc.w = fmaf(w, v.w, acc.w);
        }
    }

    *reinterpret_cast<float4*>(out + (size_t)pnt * C + q * 4) = acc;
}

extern "C" void kernel_launch(void* const* d_in, const int* in_sizes, int n_in,
                              void* d_out, int out_size, void* d_ws, size_t ws_size,
                              hipStream_t stream) {
    const float* x   = (const float*)d_in[0];
    const float* pos = (const float*)d_in[1];
    const int*   Hp  = (const int*)d_in[2];
    const int*   Wp  = (const int*)d_in[3];
    float* out = (float*)d_out;

    int total_threads = B * N * 16;           // 16 lanes per point
    int block = 256;
    int grid = (total_threads + block - 1) / block;  // 2048 blocks
    interp_sparse_bicubic<<<grid, block, 0, stream>>>(x, pos, Hp, Wp, out);
}

// Round 3
// 14.743 us; speedup vs baseline: 1.6800x; 1.6800x over previous
//
#include <hip/hip_runtime.h>
#include <hip/hip_bf16.h>

// Problem constants from setup_inputs(): x:[8,160,160,64] f32, pos:[8,4096,2] f32,
// H=W=1280 (int scalars on device). out:[8,4096,64] f32.
constexpr int B  = 8;
constexpr int Hf = 160;
constexpr int Wf = 160;
constexpr int C  = 64;
constexpr int N  = 4096;
constexpr int NXCD = 8;   // MI355X: 8 XCDs, blockIdx round-robins across them

typedef float f32x4 __attribute__((ext_vector_type(4)));  // native vec for builtins

// Bicubic (cubic convolution) weights, A = -0.75, taps at offsets -1,0,1,2.
__device__ __forceinline__ void cubic_weights(float t, float w[4]) {
    const float A = -0.75f;
    float s;
    s = t + 1.0f;                       // tap -1, s in [1,2)
    w[0] = ((A * s - 5.0f * A) * s + 8.0f * A) * s - 4.0f * A;
    s = t;                              // tap 0, s in [0,1)
    w[1] = ((A + 2.0f) * s - (A + 3.0f)) * s * s + 1.0f;
    s = 1.0f - t;                       // tap 1
    w[2] = ((A + 2.0f) * s - (A + 3.0f)) * s * s + 1.0f;
    s = 2.0f - t;                       // tap 2, s in (1,2]
    w[3] = ((A * s - 5.0f * A) * s + 8.0f * A) * s - 4.0f * A;
}

// 16 lanes per point; each lane owns one float4 channel-quad (C=64 -> 16 quads).
// Block = 256 threads = 16 points. Grid = B * (N/16) = 2048 blocks.
// XCD affinity: blockIdx % 8 selects the batch, so each XCD's L2 (4 MiB) only
// ever sees ONE batch's 6.55 MiB feature map instead of all 26 MiB.
__global__ __launch_bounds__(256)
void interp_sparse_bicubic(const float* __restrict__ x,
                           const float* __restrict__ pos,
                           const int* __restrict__ Hp,
                           const int* __restrict__ Wp,
                           float* __restrict__ out) {
    int blk  = blockIdx.x;
    int b    = blk & (NXCD - 1);         // batch == XCD slot
    int slot = blk >> 3;                 // 0 .. N/16-1
    int q    = threadIdx.x & 15;         // channel quad
    int pib  = threadIdx.x >> 4;         // point-in-block 0..15
    int n    = slot * 16 + pib;          // point within batch
    int pnt  = b * N + n;                // global point index

    float px = pos[(size_t)pnt * 2 + 0];
    float py = pos[(size_t)pnt * 2 + 1];
    float Wo = (float)Wp[0];
    float Ho = (float)Hp[0];

    // Match reference math exactly (align_corners=False chain).
    float gx = 2.0f * px / (Wo - 1.0f) - 1.0f;
    float gy = 2.0f * py / (Ho - 1.0f) - 1.0f;
    float ix = ((gx + 1.0f) * (float)Wf - 1.0f) * 0.5f;
    float iy = ((gy + 1.0f) * (float)Hf - 1.0f) * 0.5f;

    float fx = floorf(ix), fy = floorf(iy);
    float tx = ix - fx,    ty = iy - fy;
    int x0 = (int)fx, y0 = (int)fy;

    float wx[4], wy[4];
    cubic_weights(tx, wx);
    cubic_weights(ty, wy);

    const float* xb = x + (size_t)b * (Hf * Wf * C) + q * 4;

    f32x4 acc = {0.f, 0.f, 0.f, 0.f};

    #pragma unroll
    for (int i = 0; i < 4; ++i) {
        int yi = y0 - 1 + i;
        if (yi < 0 || yi >= Hf) continue;   // zeros padding
        float wyi = wy[i];
        const float* row = xb + (size_t)yi * (Wf * C);
        #pragma unroll
        for (int j = 0; j < 4; ++j) {
            int xj = x0 - 1 + j;
            if (xj < 0 || xj >= Wf) continue;
            float w = wyi * wx[j];
            f32x4 v = *reinterpret_cast<const f32x4*>(row + (size_t)xj * C);
            acc.x = fmaf(w, v.x, acc.x);
            acc.y = fmaf(w, v.y, acc.y);
            acc.z = fmaf(w, v.z, acc.z);
            acc.w = fmaf(w, v.w, acc.w);
        }
    }

    // Nontemporal: don't let the 8.4 MB output stream evict feature-map lines.
    f32x4* op = reinterpret_cast<f32x4*>(out + (size_t)pnt * C + q * 4);
    __builtin_nontemporal_store(acc, op);
}

extern "C" void kernel_launch(void* const* d_in, const int* in_sizes, int n_in,
                              void* d_out, int out_size, void* d_ws, size_t ws_size,
                              hipStream_t stream) {
    const float* x   = (const float*)d_in[0];
    const float* pos = (const float*)d_in[1];
    const int*   Hp  = (const int*)d_in[2];
    const int*   Wp  = (const int*)d_in[3];
    float* out = (float*)d_out;

    int grid = B * (N / 16);   // 2048 blocks, 16 points per 256-thread block
    interp_sparse_bicubic<<<grid, 256, 0, stream>>>(x, pos, Hp, Wp, out);
}